// Round 1
// baseline (927.098 us; speedup 1.0000x reference)
//
#include <hip/hip_runtime.h>
#include <hip/hip_bf16.h>

using bf16 = __hip_bfloat16;
typedef __bf16 bf16x8_t __attribute__((ext_vector_type(8)));
typedef float f32x4_t __attribute__((ext_vector_type(4)));

#define BM 128
#define BN 128
#define BK 64

__device__ __forceinline__ void gload_lds16(const void* g, void* l) {
  __builtin_amdgcn_global_load_lds(
      (__attribute__((address_space(1))) void*)g,
      (__attribute__((address_space(3))) void*)l, 16, 0, 0);
}

// ---------------- NT GEMM: C[m][n] = sum_k A[m][k] * B[n][k] ----------------
// EPI: 0 = bf16 out; 1 = f32 out * scale; 2 = f32 out + resid;
//      3 = bf16 out gelu(acc+bias); 4 = f32 out += (in-place) acc + bias
template <int EPI>
__global__ void gemm_nt(const bf16* __restrict__ A, const bf16* __restrict__ B,
                        void* __restrict__ Cv, int K, int lda, int ldb, int ldc,
                        long long sA, long long sB, long long sC, float scale,
                        const float* __restrict__ bias,
                        const float* __restrict__ resid, long long sR, int ldr) {
  __shared__ __align__(16) bf16 As[BM * BK];
  __shared__ __align__(16) bf16 Bs[BN * BK];
  const int tid = threadIdx.x;
  const int lane = tid & 63, wid = tid >> 6;
  const int z = blockIdx.z;
  A += (size_t)z * sA;
  B += (size_t)z * sB;
  const int bm = blockIdx.y * BM, bn = blockIdx.x * BN;
  const int wr = wid >> 1, wc = wid & 1;

  const bf16* ga[4];
  const bf16* gb[4];
  int lofs[4];
#pragma unroll
  for (int i = 0; i < 4; ++i) {
    int cb = i * 256 + wid * 64;       // wave-uniform chunk base
    int ch = cb + lane;                // this lane's 8-elem chunk
    int r = ch >> 3, c = ch & 7;
    ga[i] = A + (size_t)(bm + r) * lda + c * 8;
    gb[i] = B + (size_t)(bn + r) * ldb + c * 8;
    lofs[i] = cb * 8;                  // element offset into LDS tile
  }

  f32x4_t acc[4][4];
#pragma unroll
  for (int i = 0; i < 4; ++i)
#pragma unroll
    for (int j = 0; j < 4; ++j) acc[i][j] = (f32x4_t){0.f, 0.f, 0.f, 0.f};

  const int arow = wr * 64 + (lane & 15);
  const int brow = wc * 64 + (lane & 15);
  const int kof = (lane >> 4) * 8;

  for (int kt = 0; kt < K; kt += BK) {
#pragma unroll
    for (int i = 0; i < 4; ++i) {
      gload_lds16(ga[i] + kt, As + lofs[i]);
      gload_lds16(gb[i] + kt, Bs + lofs[i]);
    }
    __syncthreads();
#pragma unroll
    for (int kk = 0; kk < 2; ++kk) {
      bf16x8_t av[4], bv[4];
#pragma unroll
      for (int i = 0; i < 4; ++i)
        av[i] = *(const bf16x8_t*)(As + (arow + i * 16) * BK + kk * 32 + kof);
#pragma unroll
      for (int j = 0; j < 4; ++j)
        bv[j] = *(const bf16x8_t*)(Bs + (brow + j * 16) * BK + kk * 32 + kof);
#pragma unroll
      for (int i = 0; i < 4; ++i)
#pragma unroll
        for (int j = 0; j < 4; ++j)
          acc[i][j] = __builtin_amdgcn_mfma_f32_16x16x32_bf16(av[i], bv[j],
                                                              acc[i][j], 0, 0, 0);
    }
    __syncthreads();
  }

  const int row0 = bm + wr * 64 + (lane >> 4) * 4;
  const int col0 = bn + wc * 64 + (lane & 15);
#pragma unroll
  for (int i = 0; i < 4; ++i) {
#pragma unroll
    for (int j = 0; j < 4; ++j) {
#pragma unroll
      for (int jj = 0; jj < 4; ++jj) {
        const int r = row0 + i * 16 + jj;
        const int cc = col0 + j * 16;
        const float v = acc[i][j][jj];
        if constexpr (EPI == 0) {
          ((bf16*)Cv)[(size_t)z * sC + (size_t)r * ldc + cc] = __float2bfloat16(v);
        } else if constexpr (EPI == 1) {
          ((float*)Cv)[(size_t)z * sC + (size_t)r * ldc + cc] = v * scale;
        } else if constexpr (EPI == 2) {
          ((float*)Cv)[(size_t)z * sC + (size_t)r * ldc + cc] =
              v + resid[(size_t)z * sR + (size_t)r * ldr + cc];
        } else if constexpr (EPI == 3) {
          float t = v + bias[cc];
          float gl = 0.5f * t * (1.f + erff(t * 0.70710678118654752f));
          ((bf16*)Cv)[(size_t)z * sC + (size_t)r * ldc + cc] = __float2bfloat16(gl);
        } else {
          float* Cf = (float*)Cv + (size_t)z * sC;
          const size_t idx = (size_t)r * ldc + cc;
          Cf[idx] = Cf[idx] + v + bias[cc];
        }
      }
    }
  }
}

// ---------------- LayerNorm: fp32 in -> bf16 out, row length 1024 ----------
__global__ void ln_kernel(const float* __restrict__ X, const float* __restrict__ gw,
                          const float* __restrict__ bw, bf16* __restrict__ Y) {
  const int row = blockIdx.x, tid = threadIdx.x;
  const float4 xv = *(const float4*)(X + (size_t)row * 1024 + tid * 4);
  float s = xv.x + xv.y + xv.z + xv.w;
  float ss = xv.x * xv.x + xv.y * xv.y + xv.z * xv.z + xv.w * xv.w;
  __shared__ float red[8];
#pragma unroll
  for (int o = 32; o; o >>= 1) {
    s += __shfl_xor(s, o);
    ss += __shfl_xor(ss, o);
  }
  if ((tid & 63) == 0) {
    red[tid >> 6] = s;
    red[4 + (tid >> 6)] = ss;
  }
  __syncthreads();
  s = red[0] + red[1] + red[2] + red[3];
  ss = red[4] + red[5] + red[6] + red[7];
  const float mu = s * (1.f / 1024.f);
  const float var = ss * (1.f / 1024.f) - mu * mu;
  const float rs = rsqrtf(var + 1e-5f);
  const float4 gv = *(const float4*)(gw + tid * 4);
  const float4 bv = *(const float4*)(bw + tid * 4);
  union { ushort4 u; bf16 h[4]; } p;
  p.h[0] = __float2bfloat16((xv.x - mu) * rs * gv.x + bv.x);
  p.h[1] = __float2bfloat16((xv.y - mu) * rs * gv.y + bv.y);
  p.h[2] = __float2bfloat16((xv.z - mu) * rs * gv.z + bv.z);
  p.h[3] = __float2bfloat16((xv.w - mu) * rs * gv.w + bv.w);
  *(ushort4*)(Y + (size_t)row * 1024 + tid * 4) = p.u;
}

// ---------------- Softmax over rows of 2048 fp32 -> bf16 -------------------
__global__ void softmax_kernel(const float* __restrict__ S, bf16* __restrict__ P) {
  const size_t row = blockIdx.x;
  const int tid = threadIdx.x;
  const float4* sp = (const float4*)(S + row * 2048);
  const float4 v0 = sp[tid * 2], v1 = sp[tid * 2 + 1];
  float f[8] = {v0.x, v0.y, v0.z, v0.w, v1.x, v1.y, v1.z, v1.w};
  float m = f[0];
#pragma unroll
  for (int j = 1; j < 8; ++j) m = fmaxf(m, f[j]);
  __shared__ float red[4];
#pragma unroll
  for (int o = 32; o; o >>= 1) m = fmaxf(m, __shfl_xor(m, o));
  if ((tid & 63) == 0) red[tid >> 6] = m;
  __syncthreads();
  m = fmaxf(fmaxf(red[0], red[1]), fmaxf(red[2], red[3]));
  float s = 0.f;
#pragma unroll
  for (int j = 0; j < 8; ++j) {
    f[j] = expf(f[j] - m);
    s += f[j];
  }
#pragma unroll
  for (int o = 32; o; o >>= 1) s += __shfl_xor(s, o);
  __syncthreads();
  if ((tid & 63) == 0) red[tid >> 6] = s;
  __syncthreads();
  s = red[0] + red[1] + red[2] + red[3];
  const float inv = 1.f / s;
  union { uint4 u; bf16 h[8]; } p;
#pragma unroll
  for (int j = 0; j < 8; ++j) p.h[j] = __float2bfloat16(f[j] * inv);
  *(uint4*)(P + row * 2048 + tid * 8) = p.u;
}

// ------- Transpose + convert fp32 W[K][N] -> bf16 WT[rowoff+n][k] ----------
__global__ void transpose_conv(const float* __restrict__ W, bf16* __restrict__ WT,
                               int Nd, int ldT, int rowoff) {
  __shared__ float t[32][33];
  const int tx = threadIdx.x, ty = threadIdx.y;
  const int n0 = blockIdx.x * 32, k0 = blockIdx.y * 32;
#pragma unroll
  for (int j = 0; j < 4; ++j)
    t[ty + 8 * j][tx] = W[(size_t)(k0 + ty + 8 * j) * Nd + n0 + tx];
  __syncthreads();
#pragma unroll
  for (int j = 0; j < 4; ++j)
    WT[(size_t)(rowoff + n0 + ty + 8 * j) * ldT + k0 + tx] =
        __float2bfloat16(t[tx][ty + 8 * j]);
}

// ------- bf16 transpose: dst[c][r] = src[r][c], batched over z -------------
__global__ void transpose_bf16(const bf16* __restrict__ src, bf16* __restrict__ dst,
                               int ldsrc, int lddst, long long zs, long long zd) {
  __shared__ bf16 t[32][33];
  const int z = blockIdx.z;
  src += (size_t)z * zs;
  dst += (size_t)z * zd;
  const int tx = threadIdx.x, ty = threadIdx.y;
  const int c0 = blockIdx.x * 32, r0 = blockIdx.y * 32;
#pragma unroll
  for (int j = 0; j < 4; ++j)
    t[ty + 8 * j][tx] = src[(size_t)(r0 + ty + 8 * j) * ldsrc + c0 + tx];
  __syncthreads();
#pragma unroll
  for (int j = 0; j < 4; ++j)
    dst[(size_t)(c0 + ty + 8 * j) * lddst + r0 + tx] = t[tx][ty + 8 * j];
}

extern "C" void kernel_launch(void* const* d_in, const int* in_sizes, int n_in,
                              void* d_out, int out_size, void* d_ws, size_t ws_size,
                              hipStream_t stream) {
  const float* x = (const float*)d_in[0];
  const float* ln1_g = (const float*)d_in[1];
  const float* ln1_b = (const float*)d_in[2];
  const float* Wq = (const float*)d_in[3];
  const float* Wk = (const float*)d_in[4];
  const float* Wv = (const float*)d_in[5];
  const float* ln2_g = (const float*)d_in[6];
  const float* ln2_b = (const float*)d_in[7];
  const float* W1 = (const float*)d_in[8];
  const float* b1 = (const float*)d_in[9];
  const float* W2 = (const float*)d_in[10];
  const float* b2 = (const float*)d_in[11];
  float* out = (float*)d_out;

  constexpr int B = 8, N = 2048, H = 1024, F = 4096;
  constexpr int M = B * N;  // 16384

  const size_t WqkvTB = (size_t)3 * H * H * 2;
  const size_t W1TB = (size_t)H * F * 2;
  const size_t W2TB = (size_t)H * F * 2;
  const size_t yB = (size_t)M * H * 2;
  const size_t vTB = (size_t)M * H * 2;
  const size_t qkvB = (size_t)M * 3 * H * 2;
  const size_t SB1 = (size_t)N * N * 4;
  const size_t attB1 = (size_t)N * N * 2;
  const size_t hB = (size_t)M * F * 2;
  const size_t fixedB = WqkvTB + W1TB + W2TB + yB + vTB;

  int g = 8;
  for (; g > 1; g >>= 1) {
    size_t R = qkvB + (size_t)g * (SB1 + attB1);
    if (R < hB) R = hB;
    if (fixedB + R <= ws_size) break;
  }

  char* ws = (char*)d_ws;
  size_t o = 0;
  bf16* wqkvT = (bf16*)(ws + o); o += WqkvTB;
  bf16* w1T = (bf16*)(ws + o);   o += W1TB;
  bf16* w2T = (bf16*)(ws + o);   o += W2TB;
  bf16* y = (bf16*)(ws + o);     o += yB;
  bf16* vT = (bf16*)(ws + o);    o += vTB;
  char* Rb = ws + o;
  bf16* qkv = (bf16*)Rb;
  float* S = (float*)(Rb + qkvB);
  bf16* att = (bf16*)(Rb + qkvB + (size_t)g * SB1);
  bf16* h = (bf16*)Rb;  // overlays qkv/S/att after attention is done

  const dim3 tb(32, 8);
  // weight transpose+convert
  transpose_conv<<<dim3(H / 32, H / 32), tb, 0, stream>>>(Wq, wqkvT, H, H, 0);
  transpose_conv<<<dim3(H / 32, H / 32), tb, 0, stream>>>(Wk, wqkvT, H, H, H);
  transpose_conv<<<dim3(H / 32, H / 32), tb, 0, stream>>>(Wv, wqkvT, H, H, 2 * H);
  transpose_conv<<<dim3(F / 32, H / 32), tb, 0, stream>>>(W1, w1T, F, H, 0);
  transpose_conv<<<dim3(H / 32, F / 32), tb, 0, stream>>>(W2, w2T, H, F, 0);

  // LN1
  ln_kernel<<<M, 256, 0, stream>>>(x, ln1_g, ln1_b, y);

  // QKV projection: [M,H] @ WqkvT[3H,H]^T -> qkv [M,3H] bf16
  gemm_nt<0><<<dim3(3 * H / BN, M / BM, 1), 256, 0, stream>>>(
      y, wqkvT, qkv, H, H, H, 3 * H, 0, 0, 0, 1.f, nullptr, nullptr, 0, 0);

  // transpose V per batch: vT[b][d][m]
  transpose_bf16<<<dim3(H / 32, N / 32, B), tb, 0, stream>>>(
      qkv + 2 * H, vT, 3 * H, N, (long long)N * 3 * H, (long long)H * N);

  // attention in groups of g batches
  for (int b0 = 0; b0 < B; b0 += g) {
    const bf16* qb = qkv + (size_t)b0 * N * 3 * H;
    gemm_nt<1><<<dim3(N / BN, N / BM, g), 256, 0, stream>>>(
        qb, qb + H, S, H, 3 * H, 3 * H, N, (long long)N * 3 * H,
        (long long)N * 3 * H, (long long)N * N, 0.03125f, nullptr, nullptr, 0, 0);
    softmax_kernel<<<g * N, 256, 0, stream>>>(S, att);
    gemm_nt<2><<<dim3(H / BN, N / BM, g), 256, 0, stream>>>(
        att, vT + (size_t)b0 * H * N, out + (size_t)b0 * N * H, N, N, N, H,
        (long long)N * N, (long long)H * N, (long long)N * H, 1.f, nullptr,
        x + (size_t)b0 * N * H, (long long)N * H, H);
  }

  // LN2 on x2 (= d_out)
  ln_kernel<<<M, 256, 0, stream>>>(out, ln2_g, ln2_b, y);

  // FFN1: gelu(y @ W1 + b1) -> h bf16 [M,F]
  gemm_nt<3><<<dim3(F / BN, M / BM, 1), 256, 0, stream>>>(
      y, w1T, h, H, H, H, F, 0, 0, 0, 1.f, b1, nullptr, 0, 0);

  // FFN2: out += h @ W2 + b2 (in-place residual on d_out)
  gemm_nt<4><<<dim3(H / BN, M / BM, 1), 256, 0, stream>>>(
      h, w2T, out, F, F, F, H, 0, 0, 0, 1.f, b2, nullptr, 0, 0);
}